// Round 16
// baseline (93.477 us; speedup 1.0000x reference)
//
#include <hip/hip_runtime.h>
#include <hip/hip_bf16.h>

using bf16x8 = __attribute__((ext_vector_type(8))) short;
using f32x4  = __attribute__((ext_vector_type(4))) float;
using f32x2  = __attribute__((ext_vector_type(2))) float;

__device__ __forceinline__ unsigned short f2bf(float x) {
    unsigned int u = __float_as_uint(x);
    return (unsigned short)((u + 0x7FFFu + ((u >> 16) & 1u)) >> 16);
}

// -------------------------------------------------------------------------
// K0: pack text_embeddings [91][512] f32 -> [96][512] bf16 (rows 91..95 = 0)
// -------------------------------------------------------------------------
__global__ __launch_bounds__(256)
void k_prep(const float* __restrict__ te, unsigned short* __restrict__ te_bf) {
    const int r = blockIdx.x;            // 0..95
    for (int i = threadIdx.x; i < 512; i += 256) {
        const float v = (r < 91) ? te[(size_t)r * 512 + i] : 0.f;
        te_bf[(size_t)r * 512 + i] = f2bf(v);
    }
}

// -------------------------------------------------------------------------
// Per-element cost core (asm-pinned, 30 VALU; unchanged).
// -------------------------------------------------------------------------
__device__ __forceinline__ float cost_core(
    float px0, float py0, float px1, float py1,
    float pcx, float pcy, float pw, float ph, float pa,
    float tx0, float ty0, float tx1, float ty1,
    float tcx, float tcy, float tw, float th, float ta, float cc)
{
    float res, t0, t1, t2, t3, t4, t5;
    asm("v_min_f32 %[t0], %[px1], %[tx1]\n\t"
        "v_max_f32 %[t1], %[px0], %[tx0]\n\t"
        "v_sub_f32 %[t0], %[t0], %[t1]\n\t"          // dx
        "v_min_f32 %[t1], %[py1], %[ty1]\n\t"
        "v_max_f32 %[t2], %[py0], %[ty0]\n\t"
        "v_sub_f32 %[t1], %[t1], %[t2]\n\t"          // dy
        "v_max_f32 %[t2], 0, %[t0]\n\t"              // iw
        "v_max_f32 %[t3], 0, %[t1]\n\t"              // ih
        "v_mul_f32 %[t4], %[t2], %[t3]\n\t"          // inter
        "v_add_f32 %[t2], %[pw], %[tw]\n\t"
        "v_sub_f32 %[t2], %[t2], %[t0]\n\t"          // ew
        "v_add_f32 %[t3], %[ph], %[th]\n\t"
        "v_sub_f32 %[t3], %[t3], %[t1]\n\t"          // eh
        "v_mul_f32 %[t0], %[t2], %[t3]\n\t"          // ae
        "v_add_f32 %[t1], %[pa], %[ta]\n\t"
        "v_sub_f32 %[t1], %[t1], %[t4]\n\t"          // uni
        "v_sub_f32 %[t2], %[t0], %[t1]\n\t"          // ae - uni
        "v_mul_f32 %[t3], %[t1], %[t2]\n\t"          // uni*(ae-uni)
        "v_fma_f32 %[t2], %[t4], %[t0], -%[t3]\n\t"  // num
        "v_mul_f32 %[t3], %[t1], %[t0]\n\t"          // den = uni*ae
        "v_rcp_f32 %[t3], %[t3]\n\t"
        "v_sub_f32 %[t0], %[pcx], %[tcx]\n\t"
        "v_sub_f32 %[t1], %[pcy], %[tcy]\n\t"
        "v_add_f32 %[t4], |%[t0]|, |%[t1]|\n\t"
        "v_sub_f32 %[t0], %[pw], %[tw]\n\t"
        "v_sub_f32 %[t1], %[ph], %[th]\n\t"
        "v_add_f32 %[t5], |%[t0]|, |%[t1]|\n\t"
        "v_add_f32 %[t4], %[t4], %[t5]\n\t"          // l1
        "v_add_f32 %[t4], %[t4], %[cc]\n\t"          // l1 + cc
        "v_fma_f32 %[res], -%[t2], %[t3], %[t4]"     // res = l1c - num*rcp
        : [res]"=v"(res), [t0]"=&v"(t0), [t1]"=&v"(t1), [t2]"=&v"(t2),
          [t3]"=&v"(t3), [t4]"=&v"(t4), [t5]"=&v"(t5)
        : [px0]"v"(px0), [py0]"v"(py0), [px1]"v"(px1), [py1]"v"(py1),
          [pcx]"v"(pcx), [pcy]"v"(pcy), [pw]"v"(pw), [ph]"v"(ph), [pa]"v"(pa),
          [tx0]"v"(tx0), [ty0]"v"(ty0), [tx1]"v"(tx1), [ty1]"v"(ty1),
          [tcx]"v"(tcx), [tcy]"v"(tcy), [tw]"v"(tw), [th]"v"(th), [ta]"v"(ta),
          [cc]"v"(cc));
    return res;
}

// -------------------------------------------------------------------------
// FUSED (R15 structure; PROBE: ph4 cost loop repeated 3x, identical output).
// -------------------------------------------------------------------------
__global__ __launch_bounds__(256, 4)
void k_fused(const float* __restrict__ logits,     // [16384][91]
             const float* __restrict__ pboxes,     // [16384][4]
             const float* __restrict__ embed,      // [16384][512]
             const unsigned short* __restrict__ te_bf, // [96][512] bf16
             const int* __restrict__ tids,         // [1600]
             const float* __restrict__ tboxes,     // [1600][4]
             float* __restrict__ out)              // [16384][1600]
{
    union Region {
        struct { float accs[4][1536]; float sq[4][16]; } g;   // 24832 B
        struct { float cx[1600], cy[1600], w[1600], h[1600];
                 unsigned short id[1600]; } t;                // 28800 B
    };
    __shared__ Region u;
    __shared__ float cc_s[1536];      // 6144 B
    __shared__ float p_s[16 * 12];    //  768 B

    const int tid  = threadIdx.x;
    const int lane = tid & 63;
    const int wv   = tid >> 6;        // K-chunk 0..3
    const int r16  = lane & 15;
    const int q    = lane >> 4;
    const int n0   = blockIdx.x * 16;

    // ---- ph1: MFMA K-split over K-chunk [wv*128, +128)
    f32x4 acc[6];
#pragma unroll
    for (int j = 0; j < 6; ++j) acc[j] = (f32x4){0.f, 0.f, 0.f, 0.f};
    float sumsq = 0.f;

    const float* arow = embed + (size_t)(n0 + r16) * 512 + wv * 128 + q * 8;
#pragma unroll
    for (int ks = 0; ks < 4; ++ks) {
        const float4 a0 = *(const float4*)(arow + ks * 32);
        const float4 a1 = *(const float4*)(arow + ks * 32 + 4);
        sumsq = __builtin_fmaf(a0.x, a0.x, sumsq);
        sumsq = __builtin_fmaf(a0.y, a0.y, sumsq);
        sumsq = __builtin_fmaf(a0.z, a0.z, sumsq);
        sumsq = __builtin_fmaf(a0.w, a0.w, sumsq);
        sumsq = __builtin_fmaf(a1.x, a1.x, sumsq);
        sumsq = __builtin_fmaf(a1.y, a1.y, sumsq);
        sumsq = __builtin_fmaf(a1.z, a1.z, sumsq);
        sumsq = __builtin_fmaf(a1.w, a1.w, sumsq);
        union { unsigned int uw[4]; bf16x8 v; } cvt;
        asm("v_cvt_pk_bf16_f32 %0, %1, %2" : "=v"(cvt.uw[0]) : "v"(a0.x), "v"(a0.y));
        asm("v_cvt_pk_bf16_f32 %0, %1, %2" : "=v"(cvt.uw[1]) : "v"(a0.z), "v"(a0.w));
        asm("v_cvt_pk_bf16_f32 %0, %1, %2" : "=v"(cvt.uw[2]) : "v"(a1.x), "v"(a1.y));
        asm("v_cvt_pk_bf16_f32 %0, %1, %2" : "=v"(cvt.uw[3]) : "v"(a1.z), "v"(a1.w));
#pragma unroll
        for (int ct = 0; ct < 6; ++ct) {
            const bf16x8 bfr = *(const bf16x8*)(te_bf + (size_t)(ct * 16 + r16) * 512
                                                + wv * 128 + ks * 32 + q * 8);
            acc[ct] = __builtin_amdgcn_mfma_f32_16x16x32_bf16(cvt.v, bfr, acc[ct], 0, 0, 0);
        }
    }
    sumsq += __shfl_xor(sumsq, 16);
    sumsq += __shfl_xor(sumsq, 32);
    if (lane < 16) u.g.sq[wv][r16] = sumsq;

#pragma unroll
    for (int ct = 0; ct < 6; ++ct)
#pragma unroll
        for (int j = 0; j < 4; ++j)
            u.g.accs[wv][(q * 4 + j) * 96 + ct * 16 + r16] = acc[ct][j];
    __syncthreads();

    // ---- ph2: reduce + focal -> cc_s
#pragma unroll
    for (int i = 0; i < 6; ++i) {
        const int e = tid + i * 256;                 // < 1536
        const int row = e / 96, col = e - row * 96;
        float v = 0.f;
        if (col < 91) {
            const float dot = u.g.accs[0][e] + u.g.accs[1][e]
                            + u.g.accs[2][e] + u.g.accs[3][e];
            const float rn = rsqrtf(u.g.sq[0][row] + u.g.sq[1][row]
                                  + u.g.sq[2][row] + u.g.sq[3][row]);
            const float x = logits[(size_t)(n0 + row) * 91 + col];
            const float p = 1.f / (1.f + __expf(-x));
            const float pos = 0.25f * (1.f - p) * (1.f - p) * (-__logf(p + 1e-8f));
            const float neg = 0.75f * p * p * (-__logf(1.f - p + 1e-8f));
            v = (pos - neg) + 0.5f - 0.5f * dot * rn;
        }
        cc_s[e] = v;
    }
    __syncthreads();     // accs dead after this point

    // ---- ph3: stage targets SoA into union (overwrites accs) + p_s
    for (int m = tid; m < 1600; m += 256) {
        const float4 b = *(const float4*)(tboxes + (size_t)m * 4);
        u.t.cx[m] = b.x; u.t.cy[m] = b.y; u.t.w[m] = b.z; u.t.h[m] = b.w;
        u.t.id[m] = (unsigned short)tids[m];
    }
    if (tid < 16) {
        const float4 b = *(const float4*)(pboxes + (size_t)(n0 + tid) * 4);
        float* p = &p_s[tid * 12];
        p[0] = b.x; p[1] = b.y; p[2] = b.z; p[3] = b.w;
        p[4] = __builtin_fmaf(-0.5f, b.z, b.x);
        p[5] = __builtin_fmaf(-0.5f, b.w, b.y);
        p[6] = __builtin_fmaf( 0.5f, b.z, b.x);
        p[7] = __builtin_fmaf( 0.5f, b.w, b.y);
        p[8] = b.z * b.w;
    }
    __syncthreads();

    // ---- ph4 (PROBE: x3): cost loop; wave owns 4 rows, thread 2 m/chunk
    const int r4 = wv * 4;
    for (int rep = 0; rep < 3; ++rep) {
#pragma unroll
        for (int mc = 0; mc < 13; ++mc) {
            const int m  = mc * 128 + lane * 2;          // even, < 1664
            const bool valid = (m < 1600);
            const int mr = valid ? m : 1598;

            const f32x2 vcx = *(const f32x2*)&u.t.cx[mr];
            const f32x2 vcy = *(const f32x2*)&u.t.cy[mr];
            const f32x2 vw  = *(const f32x2*)&u.t.w[mr];
            const f32x2 vh  = *(const f32x2*)&u.t.h[mr];
            const unsigned int idp = *(const unsigned int*)&u.t.id[mr];
            const int ids[2] = {(int)(idp & 0xffffu), (int)(idp >> 16)};

            float tcx[2], tcy[2], tw[2], th[2];
            float tx0[2], ty0[2], tx1[2], ty1[2], ta[2];
#pragma unroll
            for (int j = 0; j < 2; ++j) {
                tcx[j] = vcx[j]; tcy[j] = vcy[j]; tw[j] = vw[j]; th[j] = vh[j];
                tx0[j] = __builtin_fmaf(-0.5f, tw[j], tcx[j]);
                ty0[j] = __builtin_fmaf(-0.5f, th[j], tcy[j]);
                tx1[j] = __builtin_fmaf( 0.5f, tw[j], tcx[j]);
                ty1[j] = __builtin_fmaf( 0.5f, th[j], tcy[j]);
                ta[j]  = tw[j] * th[j];
            }

#pragma unroll
            for (int r = 0; r < 4; ++r) {
                const int nl = r4 + r;
                const float* pr = &p_s[nl * 12];          // wave-uniform addr
                const float4 P0 = *(const float4*)pr;     // cx,cy,w,h
                const float4 P1 = *(const float4*)(pr + 4);
                const float  pa = pr[8];
                const float* ccrow = &cc_s[nl * 96];
                float res[2];
#pragma unroll
                for (int j = 0; j < 2; ++j) {
                    res[j] = cost_core(P1.x, P1.y, P1.z, P1.w,
                                       P0.x, P0.y, P0.z, P0.w, pa,
                                       tx0[j], ty0[j], tx1[j], ty1[j],
                                       tcx[j], tcy[j], tw[j], th[j], ta[j],
                                       ccrow[ids[j]]);
                }
                if (valid) {
                    f32x2 r2 = {res[0], res[1]};
                    *(f32x2*)(out + (size_t)(n0 + nl) * 1600 + m) = r2;
                }
            }
        }
        asm volatile("" ::: "memory");   // keep reps distinct
    }
}

extern "C" void kernel_launch(void* const* d_in, const int* in_sizes, int n_in,
                              void* d_out, int out_size, void* d_ws, size_t ws_size,
                              hipStream_t stream) {
    const float* pred_logits = (const float*)d_in[0];   // [16,1024,91]
    const float* pred_boxes  = (const float*)d_in[1];   // [16,1024,4]
    const float* pred_embed  = (const float*)d_in[2];   // [16,1024,512]
    const float* text_emb    = (const float*)d_in[3];   // [91,512]
    const int*   tgt_ids     = (const int*)d_in[4];     // [1600]
    const float* tgt_bbox    = (const float*)d_in[5];   // [1600,4]
    float* out = (float*)d_out;                         // [16384,1600]

    unsigned short* te_bf = (unsigned short*)d_ws;      // 96*512*2 = 96 KB

    k_prep<<<96, 256, 0, stream>>>(text_emb, te_bf);
    k_fused<<<1024, 256, 0, stream>>>(pred_logits, pred_boxes, pred_embed,
                                      te_bf, tgt_ids, tgt_bbox, out);
}

// Round 17
// 50.600 us; speedup vs baseline: 1.8474x; 1.8474x over previous
//
#include <hip/hip_runtime.h>
#include <hip/hip_bf16.h>

using bf16x8 = __attribute__((ext_vector_type(8))) short;
using f32x4  = __attribute__((ext_vector_type(4))) float;
using f32x2  = __attribute__((ext_vector_type(2))) float;

__device__ __forceinline__ unsigned short f2bf(float x) {
    unsigned int u = __float_as_uint(x);
    return (unsigned short)((u + 0x7FFFu + ((u >> 16) & 1u)) >> 16);
}

// -------------------------------------------------------------------------
// K0: pack text_embeddings [91][512] f32 -> [96][512] bf16 (rows 91..95 = 0)
// -------------------------------------------------------------------------
__global__ __launch_bounds__(256)
void k_prep(const float* __restrict__ te, unsigned short* __restrict__ te_bf) {
    const int r = blockIdx.x;            // 0..95
    for (int i = threadIdx.x; i < 512; i += 256) {
        const float v = (r < 91) ? te[(size_t)r * 512 + i] : 0.f;
        te_bf[(size_t)r * 512 + i] = f2bf(v);
    }
}

// -------------------------------------------------------------------------
// Per-element cost core (asm-pinned, 30 VALU; unchanged).
// -------------------------------------------------------------------------
__device__ __forceinline__ float cost_core(
    float px0, float py0, float px1, float py1,
    float pcx, float pcy, float pw, float ph, float pa,
    float tx0, float ty0, float tx1, float ty1,
    float tcx, float tcy, float tw, float th, float ta, float cc)
{
    float res, t0, t1, t2, t3, t4, t5;
    asm("v_min_f32 %[t0], %[px1], %[tx1]\n\t"
        "v_max_f32 %[t1], %[px0], %[tx0]\n\t"
        "v_sub_f32 %[t0], %[t0], %[t1]\n\t"          // dx
        "v_min_f32 %[t1], %[py1], %[ty1]\n\t"
        "v_max_f32 %[t2], %[py0], %[ty0]\n\t"
        "v_sub_f32 %[t1], %[t1], %[t2]\n\t"          // dy
        "v_max_f32 %[t2], 0, %[t0]\n\t"              // iw
        "v_max_f32 %[t3], 0, %[t1]\n\t"              // ih
        "v_mul_f32 %[t4], %[t2], %[t3]\n\t"          // inter
        "v_add_f32 %[t2], %[pw], %[tw]\n\t"
        "v_sub_f32 %[t2], %[t2], %[t0]\n\t"          // ew
        "v_add_f32 %[t3], %[ph], %[th]\n\t"
        "v_sub_f32 %[t3], %[t3], %[t1]\n\t"          // eh
        "v_mul_f32 %[t0], %[t2], %[t3]\n\t"          // ae
        "v_add_f32 %[t1], %[pa], %[ta]\n\t"
        "v_sub_f32 %[t1], %[t1], %[t4]\n\t"          // uni
        "v_sub_f32 %[t2], %[t0], %[t1]\n\t"          // ae - uni
        "v_mul_f32 %[t3], %[t1], %[t2]\n\t"          // uni*(ae-uni)
        "v_fma_f32 %[t2], %[t4], %[t0], -%[t3]\n\t"  // num
        "v_mul_f32 %[t3], %[t1], %[t0]\n\t"          // den = uni*ae
        "v_rcp_f32 %[t3], %[t3]\n\t"
        "v_sub_f32 %[t0], %[pcx], %[tcx]\n\t"
        "v_sub_f32 %[t1], %[pcy], %[tcy]\n\t"
        "v_add_f32 %[t4], |%[t0]|, |%[t1]|\n\t"
        "v_sub_f32 %[t0], %[pw], %[tw]\n\t"
        "v_sub_f32 %[t1], %[ph], %[th]\n\t"
        "v_add_f32 %[t5], |%[t0]|, |%[t1]|\n\t"
        "v_add_f32 %[t4], %[t4], %[t5]\n\t"          // l1
        "v_add_f32 %[t4], %[t4], %[cc]\n\t"          // l1 + cc
        "v_fma_f32 %[res], -%[t2], %[t3], %[t4]"     // res = l1c - num*rcp
        : [res]"=v"(res), [t0]"=&v"(t0), [t1]"=&v"(t1), [t2]"=&v"(t2),
          [t3]"=&v"(t3), [t4]"=&v"(t4), [t5]"=&v"(t5)
        : [px0]"v"(px0), [py0]"v"(py0), [px1]"v"(px1), [py1]"v"(py1),
          [pcx]"v"(pcx), [pcy]"v"(pcy), [pw]"v"(pw), [ph]"v"(ph), [pa]"v"(pa),
          [tx0]"v"(tx0), [ty0]"v"(ty0), [tx1]"v"(tx1), [ty1]"v"(ty1),
          [tcx]"v"(tcx), [tcy]"v"(tcy), [tw]"v"(tw), [th]"v"(th), [ta]"v"(ta),
          [cc]"v"(cc));
    return res;
}

// -------------------------------------------------------------------------
// FUSED v2: ph1 = A-prefetch (8 loads in flight) + ct-major MFMA;
//           ph4 = p-rows hoisted to registers. Else identical to R15.
// -------------------------------------------------------------------------
__global__ __launch_bounds__(256, 4)
void k_fused(const float* __restrict__ logits,     // [16384][91]
             const float* __restrict__ pboxes,     // [16384][4]
             const float* __restrict__ embed,      // [16384][512]
             const unsigned short* __restrict__ te_bf, // [96][512] bf16
             const int* __restrict__ tids,         // [1600]
             const float* __restrict__ tboxes,     // [1600][4]
             float* __restrict__ out)              // [16384][1600]
{
    union Region {
        struct { float accs[4][1536]; float sq[4][16]; } g;   // 24832 B
        struct { float cx[1600], cy[1600], w[1600], h[1600];
                 unsigned short id[1600]; } t;                // 28800 B
    };
    __shared__ Region u;
    __shared__ float cc_s[1536];      // 6144 B
    __shared__ float p_s[16 * 12];    //  768 B

    const int tid  = threadIdx.x;
    const int lane = tid & 63;
    const int wv   = tid >> 6;        // K-chunk 0..3
    const int r16  = lane & 15;
    const int q    = lane >> 4;
    const int n0   = blockIdx.x * 16;

    // ---- ph1: A prefetch (8 outstanding HBM loads), cvt once, ct-major MFMA
    const float* arow = embed + (size_t)(n0 + r16) * 512 + wv * 128 + q * 8;
    float4 A[8];
#pragma unroll
    for (int ks = 0; ks < 4; ++ks) {
        A[2 * ks]     = *(const float4*)(arow + ks * 32);
        A[2 * ks + 1] = *(const float4*)(arow + ks * 32 + 4);
    }

    float sumsq = 0.f;
    union { unsigned int uw[4]; bf16x8 v; } cvt[4];
#pragma unroll
    for (int ks = 0; ks < 4; ++ks) {
        const float4 a0 = A[2 * ks], a1 = A[2 * ks + 1];
        sumsq = __builtin_fmaf(a0.x, a0.x, sumsq);
        sumsq = __builtin_fmaf(a0.y, a0.y, sumsq);
        sumsq = __builtin_fmaf(a0.z, a0.z, sumsq);
        sumsq = __builtin_fmaf(a0.w, a0.w, sumsq);
        sumsq = __builtin_fmaf(a1.x, a1.x, sumsq);
        sumsq = __builtin_fmaf(a1.y, a1.y, sumsq);
        sumsq = __builtin_fmaf(a1.z, a1.z, sumsq);
        sumsq = __builtin_fmaf(a1.w, a1.w, sumsq);
        asm("v_cvt_pk_bf16_f32 %0, %1, %2" : "=v"(cvt[ks].uw[0]) : "v"(a0.x), "v"(a0.y));
        asm("v_cvt_pk_bf16_f32 %0, %1, %2" : "=v"(cvt[ks].uw[1]) : "v"(a0.z), "v"(a0.w));
        asm("v_cvt_pk_bf16_f32 %0, %1, %2" : "=v"(cvt[ks].uw[2]) : "v"(a1.x), "v"(a1.y));
        asm("v_cvt_pk_bf16_f32 %0, %1, %2" : "=v"(cvt[ks].uw[3]) : "v"(a1.z), "v"(a1.w));
    }

    f32x4 acc[6];
#pragma unroll
    for (int ct = 0; ct < 6; ++ct) {
        const bf16x8* bbase = (const bf16x8*)(te_bf + (size_t)(ct * 16 + r16) * 512
                                              + wv * 128 + q * 8);
        // B fragments for this ct (ks stride = 32 elems = 4 bf16x8 units)
        const bf16x8 b0 = bbase[0], b1 = bbase[4], b2 = bbase[8], b3 = bbase[12];
        f32x4 a = (f32x4){0.f, 0.f, 0.f, 0.f};
        a = __builtin_amdgcn_mfma_f32_16x16x32_bf16(cvt[0].v, b0, a, 0, 0, 0);
        a = __builtin_amdgcn_mfma_f32_16x16x32_bf16(cvt[1].v, b1, a, 0, 0, 0);
        a = __builtin_amdgcn_mfma_f32_16x16x32_bf16(cvt[2].v, b2, a, 0, 0, 0);
        a = __builtin_amdgcn_mfma_f32_16x16x32_bf16(cvt[3].v, b3, a, 0, 0, 0);
        acc[ct] = a;
    }

    sumsq += __shfl_xor(sumsq, 16);
    sumsq += __shfl_xor(sumsq, 32);
    if (lane < 16) u.g.sq[wv][r16] = sumsq;

#pragma unroll
    for (int ct = 0; ct < 6; ++ct)
#pragma unroll
        for (int j = 0; j < 4; ++j)
            u.g.accs[wv][(q * 4 + j) * 96 + ct * 16 + r16] = acc[ct][j];
    __syncthreads();

    // ---- ph2: reduce + focal -> cc_s
#pragma unroll
    for (int i = 0; i < 6; ++i) {
        const int e = tid + i * 256;                 // < 1536
        const int row = e / 96, col = e - row * 96;
        float v = 0.f;
        if (col < 91) {
            const float dot = u.g.accs[0][e] + u.g.accs[1][e]
                            + u.g.accs[2][e] + u.g.accs[3][e];
            const float rn = rsqrtf(u.g.sq[0][row] + u.g.sq[1][row]
                                  + u.g.sq[2][row] + u.g.sq[3][row]);
            const float x = logits[(size_t)(n0 + row) * 91 + col];
            const float p = 1.f / (1.f + __expf(-x));
            const float pos = 0.25f * (1.f - p) * (1.f - p) * (-__logf(p + 1e-8f));
            const float neg = 0.75f * p * p * (-__logf(1.f - p + 1e-8f));
            v = (pos - neg) + 0.5f - 0.5f * dot * rn;
        }
        cc_s[e] = v;
    }
    __syncthreads();     // accs dead after this point

    // ---- ph3: stage targets SoA into union (overwrites accs) + p_s
    for (int m = tid; m < 1600; m += 256) {
        const float4 b = *(const float4*)(tboxes + (size_t)m * 4);
        u.t.cx[m] = b.x; u.t.cy[m] = b.y; u.t.w[m] = b.z; u.t.h[m] = b.w;
        u.t.id[m] = (unsigned short)tids[m];
    }
    if (tid < 16) {
        const float4 b = *(const float4*)(pboxes + (size_t)(n0 + tid) * 4);
        float* p = &p_s[tid * 12];
        p[0] = b.x; p[1] = b.y; p[2] = b.z; p[3] = b.w;
        p[4] = __builtin_fmaf(-0.5f, b.z, b.x);
        p[5] = __builtin_fmaf(-0.5f, b.w, b.y);
        p[6] = __builtin_fmaf( 0.5f, b.z, b.x);
        p[7] = __builtin_fmaf( 0.5f, b.w, b.y);
        p[8] = b.z * b.w;
    }
    __syncthreads();

    // ---- ph4: cost loop; p-rows hoisted to registers
    const int r4 = wv * 4;
    float4 P0r[4], P1r[4];
    float  par[4];
#pragma unroll
    for (int r = 0; r < 4; ++r) {
        const float* pr = &p_s[(r4 + r) * 12];
        P0r[r] = *(const float4*)pr;
        P1r[r] = *(const float4*)(pr + 4);
        par[r] = pr[8];
    }

#pragma unroll
    for (int mc = 0; mc < 13; ++mc) {
        const int m  = mc * 128 + lane * 2;          // even, < 1664
        const bool valid = (m < 1600);
        const int mr = valid ? m : 1598;

        const f32x2 vcx = *(const f32x2*)&u.t.cx[mr];
        const f32x2 vcy = *(const f32x2*)&u.t.cy[mr];
        const f32x2 vw  = *(const f32x2*)&u.t.w[mr];
        const f32x2 vh  = *(const f32x2*)&u.t.h[mr];
        const unsigned int idp = *(const unsigned int*)&u.t.id[mr];
        const int ids[2] = {(int)(idp & 0xffffu), (int)(idp >> 16)};

        float tcx[2], tcy[2], tw[2], th[2];
        float tx0[2], ty0[2], tx1[2], ty1[2], ta[2];
#pragma unroll
        for (int j = 0; j < 2; ++j) {
            tcx[j] = vcx[j]; tcy[j] = vcy[j]; tw[j] = vw[j]; th[j] = vh[j];
            tx0[j] = __builtin_fmaf(-0.5f, tw[j], tcx[j]);
            ty0[j] = __builtin_fmaf(-0.5f, th[j], tcy[j]);
            tx1[j] = __builtin_fmaf( 0.5f, tw[j], tcx[j]);
            ty1[j] = __builtin_fmaf( 0.5f, th[j], tcy[j]);
            ta[j]  = tw[j] * th[j];
        }

#pragma unroll
        for (int r = 0; r < 4; ++r) {
            const int nl = r4 + r;
            const float* ccrow = &cc_s[nl * 96];
            float res[2];
#pragma unroll
            for (int j = 0; j < 2; ++j) {
                res[j] = cost_core(P1r[r].x, P1r[r].y, P1r[r].z, P1r[r].w,
                                   P0r[r].x, P0r[r].y, P0r[r].z, P0r[r].w, par[r],
                                   tx0[j], ty0[j], tx1[j], ty1[j],
                                   tcx[j], tcy[j], tw[j], th[j], ta[j],
                                   ccrow[ids[j]]);
            }
            if (valid) {
                f32x2 r2 = {res[0], res[1]};
                *(f32x2*)(out + (size_t)(n0 + nl) * 1600 + m) = r2;
            }
        }
    }
}

extern "C" void kernel_launch(void* const* d_in, const int* in_sizes, int n_in,
                              void* d_out, int out_size, void* d_ws, size_t ws_size,
                              hipStream_t stream) {
    const float* pred_logits = (const float*)d_in[0];   // [16,1024,91]
    const float* pred_boxes  = (const float*)d_in[1];   // [16,1024,4]
    const float* pred_embed  = (const float*)d_in[2];   // [16,1024,512]
    const float* text_emb    = (const float*)d_in[3];   // [91,512]
    const int*   tgt_ids     = (const int*)d_in[4];     // [1600]
    const float* tgt_bbox    = (const float*)d_in[5];   // [1600,4]
    float* out = (float*)d_out;                         // [16384,1600]

    unsigned short* te_bf = (unsigned short*)d_ws;      // 96*512*2 = 96 KB

    k_prep<<<96, 256, 0, stream>>>(text_emb, te_bf);
    k_fused<<<1024, 256, 0, stream>>>(pred_logits, pred_boxes, pred_embed,
                                      te_bf, tgt_ids, tgt_bbox, out);
}